// Round 8
// baseline (477.328 us; speedup 1.0000x reference)
//
#include <hip/hip_runtime.h>

#define OUT_H 7
#define OUT_W 7
#define FEAT_H 200
#define FEAT_W 200
#define HW_ALL (FEAT_H * FEAT_W)
#define CH 64        // channels staged per chunk
#define LS 67        // LDS x-stride (floats): 67%32=3, gcd(3,32)=1 -> conflict-free

// ---------------- Fused RoIAlign, direct from NCHW fp32 ----------------
// Block = (roi n, output row jy). Stage the 2 needed feature rows' x-span
// (<=66 contiguous floats) for 64 channels at a time into LDS with coalesced
// row reads (one wave per row, lane = x). Then each thread bilinear-samples
// from LDS and writes out[n][c][jy][jx] directly. No workspace round-trip.
__global__ __launch_bounds__(256) void roialign_fused(
    const float* __restrict__ feat,   // (B, 256, 200, 200)
    const int*   __restrict__ rois,   // (N, 5): b, x1, y1, x2, y2
    float*       __restrict__ out,    // (N, 256, 7, 7)
    int N)
{
    __shared__ float lds[2 * CH * LS];   // 33.5 KB -> 4 blocks/CU

    int n  = blockIdx.x / OUT_H;
    int jy = blockIdx.x % OUT_H;

    const int* r = rois + n * 5;
    int   b   = r[0];
    float x1f = (float)r[1];
    float y1f = (float)r[2];
    float dx  = (float)r[3] - x1f;
    float dy  = (float)r[4] - y1f;

    // Row pair for this jy (uniform across block). Match reference op order.
    float sy   = y1f + ((float)jy * dy) / 6.0f;
    float y0fl = floorf(sy);
    float wy   = sy - y0fl;
    int y0  = min(max((int)y0fl, 0), FEAT_H - 1);
    int y1i = min(y0 + 1, FEAT_H - 1);
    float omwy = 1.0f - wy;

    // x-span covering all 7 jx corner columns: [xs, xe], wspan <= 66.
    int xs = min(max((int)floorf(x1f), 0), FEAT_W - 1);
    int xe = min((int)floorf(x1f + dx) + 1, FEAT_W - 1);
    int wspan = xe - xs + 1;

    int t    = threadIdx.x;
    int wave = t >> 6;
    int lane = t & 63;
    int c    = t & 63;       // compute-phase channel within chunk
    int slot = t >> 6;       // compute-phase jx slot (jx = slot, slot+4)

    int yrow[2];
    yrow[0] = y0;
    yrow[1] = y1i;

    size_t cbase = (size_t)b * 256 * HW_ALL;

    for (int cg = 0; cg < 4; ++cg) {
        __syncthreads();
        // ---- stage: 128 rows (2 y x 64 c), one wave per row, lane = x ----
        for (int rr = wave; rr < 2 * CH; rr += 4) {
            int yy = rr >> 6;          // 0/1
            int cc = rr & 63;
            const float* src = feat + cbase
                             + (size_t)(cg * CH + cc) * HW_ALL
                             + yrow[yy] * FEAT_W + xs;
            float* dst = &lds[rr * LS];
            if (lane < wspan) dst[lane] = src[lane];
            int xt = 64 + lane;
            if (xt < wspan) dst[xt] = src[xt];   // tail (wspan up to 66)
        }
        __syncthreads();

        // ---- compute: c = t&63, jx in {slot, slot+4} ----
        const float* l0 = &lds[c * LS];            // yy=0 row for channel c
        const float* l1 = &lds[(CH + c) * LS];     // yy=1 row
        float* ob = out + (((size_t)n * 256 + cg * CH + c) * OUT_H + jy) * OUT_W;

#pragma unroll
        for (int j = 0; j < 2; ++j) {
            int jx = slot + (j << 2);
            if (jx < OUT_W) {
                float sx   = x1f + ((float)jx * dx) / 6.0f;
                float x0fl = floorf(sx);
                float wx   = sx - x0fl;
                int x0  = min(max((int)x0fl, 0), FEAT_W - 1);
                int x1i = min(x0 + 1, FEAT_W - 1);
                float omwx = 1.0f - wx;
                int xi0 = x0  - xs;
                int xi1 = x1i - xs;

                float v00 = l0[xi0], v01 = l0[xi1];
                float v10 = l1[xi0], v11 = l1[xi1];

                ob[jx] = v00 * (omwy * omwx) + v01 * (omwy * wx)
                       + v10 * (wy   * omwx) + v11 * (wy   * wx);
            }
        }
    }
}

// ---------------- Fallback: direct NCHW gather (geometry mismatch) ----------------
__global__ __launch_bounds__(256) void roialign_direct(
    const float* __restrict__ feat, const int* __restrict__ rois,
    float* __restrict__ out, int C, int H, int W, int total)
{
    int idx = blockIdx.x * blockDim.x + threadIdx.x;
    if (idx >= total) return;
    int jx = idx % OUT_W;
    int t  = idx / OUT_W;
    int jy = t % OUT_H;
    t /= OUT_H;
    int c = t % C;
    int n = t / C;
    const int* r = rois + n * 5;
    int b = r[0];
    float x1 = (float)r[1], y1 = (float)r[2];
    float x2 = (float)r[3], y2 = (float)r[4];
    float sy = y1 + ((float)jy * (y2 - y1)) / (float)(OUT_H - 1);
    float sx = x1 + ((float)jx * (x2 - x1)) / (float)(OUT_W - 1);
    float y0f = floorf(sy), x0f = floorf(sx);
    float wy = sy - y0f, wx = sx - x0f;
    int y0  = min(max((int)y0f, 0), H - 1);
    int y1i = min(y0 + 1, H - 1);
    int x0  = min(max((int)x0f, 0), W - 1);
    int x1i = min(x0 + 1, W - 1);
    const float* fp = feat + ((size_t)b * C + c) * (size_t)(H * W);
    float v00 = fp[y0  * W + x0 ];
    float v01 = fp[y0  * W + x1i];
    float v10 = fp[y1i * W + x0 ];
    float v11 = fp[y1i * W + x1i];
    float omwy = 1.0f - wy, omwx = 1.0f - wx;
    out[idx] = v00 * omwy * omwx + v01 * omwy * wx
             + v10 * wy   * omwx + v11 * wy   * wx;
}

extern "C" void kernel_launch(void* const* d_in, const int* in_sizes, int n_in,
                              void* d_out, int out_size, void* d_ws, size_t ws_size,
                              hipStream_t stream)
{
    const float* feat = (const float*)d_in[0];
    const int*   rois = (const int*)d_in[1];
    float*       out  = (float*)d_out;

    int N  = in_sizes[1] / 5;                        // 512
    int C  = out_size / (N * OUT_H * OUT_W);         // 256
    int B  = in_sizes[0] / (C * HW_ALL);             // 4 when geometry matches

    if (C == 256 && in_sizes[0] == B * 256 * HW_ALL && B >= 1) {
        roialign_fused<<<N * OUT_H, 256, 0, stream>>>(feat, rois, out, N);
    } else {
        int H = FEAT_H, W = FEAT_W;
        int total = out_size;
        roialign_direct<<<(total + 255) / 256, 256, 0, stream>>>(feat, rois, out, C, H, W, total);
    }
}

// Round 9
// 257.143 us; speedup vs baseline: 1.8563x; 1.8563x over previous
//
#include <hip/hip_runtime.h>
#include <hip/hip_bf16.h>
#include <string.h>

#define OUT_H 7
#define OUT_W 7
#define FEAT_H 200
#define FEAT_W 200
#define HW_ALL (FEAT_H * FEAT_W)
#define THW 160          // hw per transpose tile (40000 % 160 == 0 -> 250 tiles)
#define TLS 161          // LDS row stride (floats); 161%32==1 -> ~2-way conflicts max

__device__ inline unsigned pack2_bf16(float a, float b) {
    __hip_bfloat16 ha = __float2bfloat16(a);
    __hip_bfloat16 hb = __float2bfloat16(b);
    unsigned short ua, ub;
    memcpy(&ua, &ha, 2);
    memcpy(&ub, &hb, 2);
    return (unsigned)ua | ((unsigned)ub << 16);
}

// ---------------- Kernel 1: NCHW fp32 -> blocked-NHWC bf16 ----------------
// featT layout: (B, C/64, HW, 64ch) bf16. Per block: 64 ch x 160 hw.
// Reads: 640 B contiguous per channel run. Writes: 20 KB fully contiguous.
__global__ __launch_bounds__(256) void nchw_to_blocked_v4(
    const float* __restrict__ feat,   // (B, 256, HW)
    uint2*       __restrict__ featT,  // (B, 4, HW, 16) uint2 (=64ch bf16)
    int HW)
{
    __shared__ float tile[64 * TLS];     // 41.2 KB -> 3 blocks/CU
    int hw0 = blockIdx.x * THW;
    int cg  = blockIdx.y;                // channel group 0..3
    int b   = blockIdx.z;
    const float* src = feat + ((size_t)b * 256 + cg * 64) * HW + hw0;
    int t = threadIdx.x;

    // ---- stage: 64 ch x 40 float4 = 2560 float4, 10 per thread ----
#pragma unroll
    for (int i = 0; i < 10; ++i) {
        int flat = i * 256 + t;          // 0..2559
        int c = flat / 40;               // channel 0..63
        int q = flat % 40;               // float4 index within 160-hw run
        float4 v = *(const float4*)(src + (size_t)c * HW + q * 4);
        float* d = &tile[c * TLS + q * 4];
        d[0] = v.x; d[1] = v.y; d[2] = v.z; d[3] = v.w;
    }
    __syncthreads();

    // ---- write: 160 hw x 16 uint2 = 2560 uint2, fully contiguous ----
    uint2* dst = featT + ((size_t)(b * 4 + cg) * HW + hw0) * 16;
#pragma unroll
    for (int i = 0; i < 10; ++i) {
        int o  = i * 256 + t;            // 0..2559, == hw*16 + cq
        int hw = o >> 4;
        int cq = o & 15;                 // channels cq*4 .. cq*4+3
        float a0 = tile[(cq * 4 + 0) * TLS + hw];
        float a1 = tile[(cq * 4 + 1) * TLS + hw];
        float a2 = tile[(cq * 4 + 2) * TLS + hw];
        float a3 = tile[(cq * 4 + 3) * TLS + hw];
        uint2 u;
        u.x = pack2_bf16(a0, a1);
        u.y = pack2_bf16(a2, a3);
        dst[o] = u;
    }
}

// ---------------- Kernel 2: RoIAlign on blocked-NHWC bf16 ----------------
// Block = (roi n, channel group cg): 2048 blocks, 64 ch each, LDS 12.5 KB.
// Thread: cq = t&15 (4-ch quad), pg = t>>4 (16 position groups).
// Corner read: 16 lanes x uint2 = 128 B contiguous.
__global__ __launch_bounds__(256) void roialign_blocked_v4(
    const uint2* __restrict__ featT,   // (B, 4, HW, 16) uint2
    const int*   __restrict__ rois,    // (N, 5)
    float*       __restrict__ out)     // (N, 256, 49)
{
    __shared__ float acc[64 * OUT_H * OUT_W];    // 12.5 KB
    const int H = FEAT_H, W = FEAT_W;
    int n  = blockIdx.x >> 2;
    int cg = blockIdx.x & 3;
    const int* r = rois + n * 5;
    int   b   = r[0];
    float x1f = (float)r[1];
    float y1f = (float)r[2];
    float dx  = (float)r[3] - x1f;
    float dy  = (float)r[4] - y1f;

    int t  = threadIdx.x;
    int cq = t & 15;
    int pg = t >> 4;                     // 0..15
    const uint2* fb = featT + ((size_t)(b * 4 + cg) * HW_ALL) * 16 + cq;

#define BFLO(u) __uint_as_float((u) << 16)
#define BFHI(u) __uint_as_float((u) & 0xffff0000u)

#pragma unroll
    for (int pi = 0; pi < 4; ++pi) {
        int p = (pi << 4) + pg;
        if (p < 49) {
            int jy = p / 7, jx = p % 7;
            float sy = y1f + ((float)jy * dy) / 6.0f;
            float sx = x1f + ((float)jx * dx) / 6.0f;
            float y0fl = floorf(sy), x0fl = floorf(sx);
            float wy = sy - y0fl,    wx = sx - x0fl;
            int y0  = min(max((int)y0fl, 0), H - 1);
            int y1i = min(y0 + 1, H - 1);
            int x0  = min(max((int)x0fl, 0), W - 1);
            int x1i = min(x0 + 1, W - 1);
            float omwy = 1.0f - wy, omwx = 1.0f - wx;
            float w00 = omwy * omwx, w01 = omwy * wx;
            float w10 = wy * omwx,   w11 = wy * wx;

            uint2 u00 = fb[(size_t)(y0  * W + x0 ) * 16];
            uint2 u01 = fb[(size_t)(y0  * W + x1i) * 16];
            uint2 u10 = fb[(size_t)(y1i * W + x0 ) * 16];
            uint2 u11 = fb[(size_t)(y1i * W + x1i) * 16];

            float r0 = BFLO(u00.x)*w00 + BFLO(u01.x)*w01 + BFLO(u10.x)*w10 + BFLO(u11.x)*w11;
            float r1 = BFHI(u00.x)*w00 + BFHI(u01.x)*w01 + BFHI(u10.x)*w10 + BFHI(u11.x)*w11;
            float r2 = BFLO(u00.y)*w00 + BFLO(u01.y)*w01 + BFLO(u10.y)*w10 + BFLO(u11.y)*w11;
            float r3 = BFHI(u00.y)*w00 + BFHI(u01.y)*w01 + BFHI(u10.y)*w10 + BFHI(u11.y)*w11;

            int c0 = cq << 2;            // local channel base 0..60
            acc[(c0 + 0) * 49 + p] = r0;
            acc[(c0 + 1) * 49 + p] = r1;
            acc[(c0 + 2) * 49 + p] = r2;
            acc[(c0 + 3) * 49 + p] = r3;
        }
    }
    __syncthreads();

    // acc local flat order == out[n, cg*64 + cl, p] flat order; 3136 floats.
    float* ob = out + ((size_t)n * 256 + cg * 64) * (OUT_H * OUT_W);
    const int total = 64 * OUT_H * OUT_W;
    for (int k = t; k < total; k += 256)
        ob[k] = acc[k];
}

// ---------------- Fallback: direct NCHW gather ----------------
__global__ __launch_bounds__(256) void roialign_direct(
    const float* __restrict__ feat, const int* __restrict__ rois,
    float* __restrict__ out, int C, int H, int W, int total)
{
    int idx = blockIdx.x * blockDim.x + threadIdx.x;
    if (idx >= total) return;
    int jx = idx % OUT_W;
    int t  = idx / OUT_W;
    int jy = t % OUT_H;
    t /= OUT_H;
    int c = t % C;
    int n = t / C;
    const int* r = rois + n * 5;
    int b = r[0];
    float x1 = (float)r[1], y1 = (float)r[2];
    float x2 = (float)r[3], y2 = (float)r[4];
    float sy = y1 + ((float)jy * (y2 - y1)) / (float)(OUT_H - 1);
    float sx = x1 + ((float)jx * (x2 - x1)) / (float)(OUT_W - 1);
    float y0f = floorf(sy), x0f = floorf(sx);
    float wy = sy - y0f, wx = sx - x0f;
    int y0  = min(max((int)y0f, 0), H - 1);
    int y1i = min(y0 + 1, H - 1);
    int x0  = min(max((int)x0f, 0), W - 1);
    int x1i = min(x0 + 1, W - 1);
    const float* fp = feat + ((size_t)b * C + c) * (size_t)(H * W);
    float v00 = fp[y0  * W + x0 ];
    float v01 = fp[y0  * W + x1i];
    float v10 = fp[y1i * W + x0 ];
    float v11 = fp[y1i * W + x1i];
    float omwy = 1.0f - wy, omwx = 1.0f - wx;
    out[idx] = v00 * omwy * omwx + v01 * omwy * wx
             + v10 * wy   * omwx + v11 * wy   * wx;
}

extern "C" void kernel_launch(void* const* d_in, const int* in_sizes, int n_in,
                              void* d_out, int out_size, void* d_ws, size_t ws_size,
                              hipStream_t stream)
{
    const float* feat = (const float*)d_in[0];
    const int*   rois = (const int*)d_in[1];
    float*       out  = (float*)d_out;

    int N  = in_sizes[1] / 5;                        // 512
    int C  = out_size / (N * OUT_H * OUT_W);         // 256
    int B  = in_sizes[0] / (C * HW_ALL);             // 4 when geometry matches

    size_t need = (size_t)B * HW_ALL * 256 * sizeof(__hip_bfloat16);  // 82 MB
    if (C == 256 && in_sizes[0] == B * 256 * HW_ALL && ws_size >= need) {
        uint2* featT = (uint2*)d_ws;
        dim3 tgrid(HW_ALL / THW, 4, B);              // 250 x 4 x B
        nchw_to_blocked_v4<<<tgrid, 256, 0, stream>>>(feat, featT, HW_ALL);
        roialign_blocked_v4<<<N * 4, 256, 0, stream>>>(featT, rois, out);
    } else {
        int total = out_size;
        roialign_direct<<<(total + 255) / 256, 256, 0, stream>>>(
            feat, rois, out, C, FEAT_H, FEAT_W, total);
    }
}